// Round 8
// baseline (22.211 us; speedup 1.0000x reference)
//
#include <hip/hip_runtime.h>

// out[f] = sum_n w[n] * (2/sqrt(pi)) * c[n]^2 * arg * exp(-arg^2),
//   arg = (B_mean[n] - B_val[f]) * c[n], reference-masked to |arg| <= 2.5.
//
// Round-8: same packed-FP32 recurrence inner loop as r6/r7 (verified).
//   - CHUNK 64->128: partial buffer 4 MB -> 2 MB (512 rows), half the
//     blocks, prologue amortized 2x. (1 wave/SIMD: dense-ALU loop with
//     unroll-4 pair ILP tolerates it -- falsifiable this round.)
//   - stage-2: float4 loads, 32 row-slices, two-level LDS tree, float4 out.

namespace {
constexpr float K_2_SQRT_PI = 1.1283791670955126f;  // 2/sqrt(pi)
constexpr float LOG2E       = 1.4426950408889634f;
constexpr int BLOCK = 128;   // threads per stage-1 block (2 waves)
constexpr int FPT   = 8;     // consecutive fields per thread
constexpr int NFT   = BLOCK * FPT;  // fields per tile (1024)
constexpr int CHUNK = 128;   // lines per stage-1 block (64 pairs)
}

typedef float v2f __attribute__((ext_vector_type(2)));

#define PK_FMA_ACC(acc, a, b) \
    asm("v_pk_fma_f32 %0, %1, %2, %0" : "+v"(acc) : "v"(a), "v"(b))
#define PK_MUL_IN(x, y) \
    asm("v_pk_mul_f32 %0, %0, %1" : "+v"(x) : "v"(y))
#define PK_ADD_IN(x, y) \
    asm("v_pk_add_f32 %0, %0, %1" : "+v"(x) : "v"(y))

// ---------------- Stage 1: packed-pair recurrence partials ----------------
__global__ __launch_bounds__(BLOCK, 4) void spectra_partial_kernel(
    const float* __restrict__ B_mean,
    const float* __restrict__ c_ext,
    const float* __restrict__ B_val,
    const float* __restrict__ weights,
    float* __restrict__ part,            // [n_chunks][nft*NFT]
    int n_lines, int n_fields, int nft)
{
    __shared__ float4 sA[CHUNK / 2];   // {bm0, bm1, cl0, cl1}
    __shared__ float4 sB[CHUNK / 2];   // {s30, s31, q0, q1}
    const int tid  = threadIdx.x;
    const int base = blockIdx.x * CHUNK;

    // Uniform grid step from the first two grid points.
    const float dB = B_val[1] - B_val[0];

    if (tid < CHUNK) {
        const int n = base + tid;
        float bm = 0.0f, cc = 1.0f, ww = 0.0f;
        const bool valid = (n < n_lines);
        if (valid) { bm = B_mean[n]; cc = c_ext[n]; ww = weights[n]; }
        const float c2 = cc * cc;
        const float cl = c2 * LOG2E;
        const float s3 = valid ? (K_2_SQRT_PI * ww * c2 * cc) : 0.0f;
        const float q  = __builtin_amdgcn_exp2f(-2.0f * cl * dB * dB);
        const int p = tid >> 1, k = tid & 1;
        float* pA = (float*)sA;
        float* pB = (float*)sB;
        pA[4 * p + k]     = bm;
        pA[4 * p + 2 + k] = cl;
        pB[4 * p + k]     = s3;
        pB[4 * p + 2 + k] = q;
    }
    __syncthreads();

    const int ft  = blockIdx.y;
    const int f0g = ft * NFT + tid * FPT;
    const float bv = (f0g < n_fields) ? B_val[f0g] : 0.0f;

    const v2f ndB2  = { -dB, -dB };
    const float twodB = 2.0f * dB;
    const float nhdB  = -0.5f * dB;

    v2f acc[FPT];
#pragma unroll
    for (int k = 0; k < FPT; ++k) acc[k] = (v2f){0.0f, 0.0f};

#pragma unroll 4
    for (int p = 0; p < CHUNK / 2; ++p) {
        const float4 a = sA[p];          // broadcast ds_read_b128
        const float4 b = sB[p];          // broadcast ds_read_b128
        const v2f bm2 = { a.x, a.y };
        const v2f cl2 = { a.z, a.w };
        const v2f s32 = { b.x, b.y };
        v2f q2        = { b.z, b.w };

        v2f d = bm2;
        d.x -= bv; d.y -= bv;
        const v2f A2  = { cl2.x * twodB, cl2.y * twodB };   // 2 cl dB
        const v2f Bc2 = { A2.x * nhdB,   A2.y * nhdB };     // -cl dB^2
        const v2f u   = { (cl2.x * d.x) * d.x, (cl2.y * d.y) * d.y };
        v2f g = { __builtin_amdgcn_exp2f(-u.x) * s32.x,
                  __builtin_amdgcn_exp2f(-u.y) * s32.y };
        v2f h = { __builtin_amdgcn_exp2f(fmaf(A2.x, d.x, Bc2.x)),
                  __builtin_amdgcn_exp2f(fmaf(A2.y, d.y, Bc2.y)) };

#pragma unroll
        for (int k = 0; k < FPT; ++k) {
            PK_FMA_ACC(acc[k], d, g);    // acc += d * g  (2 lines packed)
            if (k < FPT - 1) {
                PK_MUL_IN(g, h);         // g *= h
                PK_MUL_IN(h, q2);        // h *= q
                PK_ADD_IN(d, ndB2);      // d -= dB
            }
        }
    }

    // Combine line-slots; store this thread's 8-field partial (two float4).
    const int rowlen = nft * NFT;
    float* row = part + (size_t)blockIdx.x * rowlen + ft * NFT + tid * FPT;
    *reinterpret_cast<float4*>(row) =
        make_float4(acc[0].x + acc[0].y, acc[1].x + acc[1].y,
                    acc[2].x + acc[2].y, acc[3].x + acc[3].y);
    *reinterpret_cast<float4*>(row + 4) =
        make_float4(acc[4].x + acc[4].y, acc[5].x + acc[5].y,
                    acc[6].x + acc[6].y, acc[7].x + acc[7].y);
}

// ---------------- Stage 2: wide coalesced column-sum -> out ----------------
// Block covers 32 fields (8 float4 quads). 256 threads: quad = t&7
// (128 B contiguous per 8 lanes), row-slice = t>>3 (32 slices).
__global__ __launch_bounds__(256) void spectra_reduce_kernel(
    const float4* __restrict__ part4, float* __restrict__ out,
    int n_chunks, int n_fields, int rowlen4)   // rowlen4 = rowlen/4
{
    __shared__ float4 red[32][8];
    __shared__ float4 red2[8][8];
    const int t = threadIdx.x;
    const int q = t & 7;          // field-quad within the 32-field group
    const int s = t >> 3;         // row slice 0..31
    const int base4 = blockIdx.x * 8;

    float4 a = make_float4(0.f, 0.f, 0.f, 0.f);
    if (base4 + q < rowlen4) {
#pragma unroll 4
        for (int p = s; p < n_chunks; p += 32) {
            const float4 v = part4[(size_t)p * rowlen4 + base4 + q];
            a.x += v.x; a.y += v.y; a.z += v.z; a.w += v.w;
        }
    }
    red[s][q] = a;
    __syncthreads();

    if (t < 64) {
        const int qq = t & 7, g = t >> 3;
        const float4 r0 = red[g * 4 + 0][qq];
        const float4 r1 = red[g * 4 + 1][qq];
        const float4 r2 = red[g * 4 + 2][qq];
        const float4 r3 = red[g * 4 + 3][qq];
        red2[g][qq] = make_float4(r0.x + r1.x + r2.x + r3.x,
                                  r0.y + r1.y + r2.y + r3.y,
                                  r0.z + r1.z + r2.z + r3.z,
                                  r0.w + r1.w + r2.w + r3.w);
    }
    __syncthreads();

    if (t < 8) {
        float4 a0 = make_float4(0.f, 0.f, 0.f, 0.f);
#pragma unroll
        for (int g = 0; g < 8; ++g) {
            const float4 r = red2[g][t];
            a0.x += r.x; a0.y += r.y; a0.z += r.z; a0.w += r.w;
        }
        const int f = blockIdx.x * 32 + t * 4;
        if (f + 4 <= n_fields) {
            *reinterpret_cast<float4*>(&out[f]) = a0;
        } else {
            if (f + 0 < n_fields) out[f + 0] = a0.x;
            if (f + 1 < n_fields) out[f + 1] = a0.y;
            if (f + 2 < n_fields) out[f + 2] = a0.z;
            if (f + 3 < n_fields) out[f + 3] = a0.w;
        }
    }
}

// ---------------- Fallback (tiny ws): exact masked atomic path -----------
__global__ void zero_out_kernel(float* __restrict__ out, int n) {
    int i = blockIdx.x * blockDim.x + threadIdx.x;
    if (i < n) out[i] = 0.0f;
}

__global__ __launch_bounds__(1024) void spectra_atomic_kernel(
    const float* __restrict__ B_mean,
    const float* __restrict__ c_ext,
    const float* __restrict__ B_val,
    const float* __restrict__ weights,
    float* __restrict__ out,
    int n_lines, int n_fields)
{
    __shared__ float4 lds[256];
    const int tid  = threadIdx.x;
    const int base = blockIdx.x * 256;
    if (tid < 256) {
        const int n = base + tid;
        float bm = 0.0f, cc = 0.0f, ww = 0.0f;
        if (n < n_lines) { bm = B_mean[n]; cc = c_ext[n]; ww = weights[n]; }
        const float c2 = cc * cc;
        lds[tid] = make_float4(bm, c2 * LOG2E, K_2_SQRT_PI * ww * c2 * cc, 0.0f);
    }
    __syncthreads();
    const int f = tid;
    const float bv = (f < n_fields) ? B_val[f] : 0.0f;
    const int nl = min(256, n_lines - base);
    float acc = 0.0f;
#pragma unroll 4
    for (int i = 0; i < nl; ++i) {
        const float4 L = lds[i];
        const float d = L.x - bv;
        const float u = (L.y * d) * d;
        const float e = __builtin_amdgcn_exp2f(-u);
        acc += (L.z * d) * ((u <= 6.25f * LOG2E) ? e : 0.0f);
    }
    if (f < n_fields) atomicAdd(&out[f], acc);
}

extern "C" void kernel_launch(void* const* d_in, const int* in_sizes, int n_in,
                              void* d_out, int out_size, void* d_ws, size_t ws_size,
                              hipStream_t stream) {
    const float* B_mean  = (const float*)d_in[0];
    const float* c_ext   = (const float*)d_in[1];
    const float* B_val   = (const float*)d_in[2];
    const float* weights = (const float*)d_in[3];
    float* out = (float*)d_out;

    const int n_lines  = in_sizes[0];
    const int n_fields = in_sizes[2];

    const int n_chunks = (n_lines + CHUNK - 1) / CHUNK;
    const int nft      = (n_fields + NFT - 1) / NFT;
    const int rowlen   = nft * NFT;
    const size_t part_bytes = (size_t)n_chunks * rowlen * sizeof(float);

    if (part_bytes > ws_size || n_fields < 2) {
        zero_out_kernel<<<(out_size + 255) / 256, 256, 0, stream>>>(out, out_size);
        spectra_atomic_kernel<<<(n_lines + 255) / 256, 1024, 0, stream>>>(
            B_mean, c_ext, B_val, weights, out, n_lines, n_fields);
        return;
    }

    float* part = (float*)d_ws;

    dim3 grid1(n_chunks, nft);
    spectra_partial_kernel<<<grid1, BLOCK, 0, stream>>>(
        B_mean, c_ext, B_val, weights, part, n_lines, n_fields, nft);

    spectra_reduce_kernel<<<(rowlen + 31) / 32, 256, 0, stream>>>(
        reinterpret_cast<const float4*>(part), out,
        n_chunks, n_fields, rowlen / 4);
}

// Round 9
// 18.334 us; speedup vs baseline: 1.2114x; 1.2114x over previous
//
#include <hip/hip_runtime.h>

// out[f] = sum_n w[n] * (2/sqrt(pi)) * c[n]^2 * arg * exp(-arg^2),
//   arg = (B_mean[n] - B_val[f]) * c[n], reference-masked to |arg| <= 2.5.
//
// Round-9: stage-1 identical to r7 (CHUNK=64, 2 waves/SIMD -- measured best,
// 21.6us total). Stage-2 rebuilt: 64 blocks x 16 fields, float4 loads
// (64B contiguous per 4 lanes), 64 row-slices, two-level LDS tree.

namespace {
constexpr float K_2_SQRT_PI = 1.1283791670955126f;  // 2/sqrt(pi)
constexpr float LOG2E       = 1.4426950408889634f;
constexpr int BLOCK = 128;   // threads per stage-1 block (2 waves)
constexpr int FPT   = 8;     // consecutive fields per thread
constexpr int NFT   = BLOCK * FPT;  // fields per tile (1024)
constexpr int CHUNK = 64;    // lines per stage-1 block (32 pairs)
}

typedef float v2f __attribute__((ext_vector_type(2)));

#define PK_FMA_ACC(acc, a, b) \
    asm("v_pk_fma_f32 %0, %1, %2, %0" : "+v"(acc) : "v"(a), "v"(b))
#define PK_MUL_IN(x, y) \
    asm("v_pk_mul_f32 %0, %0, %1" : "+v"(x) : "v"(y))
#define PK_ADD_IN(x, y) \
    asm("v_pk_add_f32 %0, %0, %1" : "+v"(x) : "v"(y))

// ---------------- Stage 1: packed-pair recurrence partials (r7) -----------
__global__ __launch_bounds__(BLOCK, 4) void spectra_partial_kernel(
    const float* __restrict__ B_mean,
    const float* __restrict__ c_ext,
    const float* __restrict__ B_val,
    const float* __restrict__ weights,
    float* __restrict__ part,            // [n_chunks][nft*NFT]
    int n_lines, int n_fields, int nft)
{
    __shared__ float4 sA[CHUNK / 2];   // {bm0, bm1, cl0, cl1}
    __shared__ float4 sB[CHUNK / 2];   // {s30, s31, q0, q1}
    const int tid  = threadIdx.x;
    const int base = blockIdx.x * CHUNK;

    // Uniform grid step from the first two grid points.
    const float dB = B_val[1] - B_val[0];

    if (tid < CHUNK) {
        const int n = base + tid;
        float bm = 0.0f, cc = 1.0f, ww = 0.0f;
        const bool valid = (n < n_lines);
        if (valid) { bm = B_mean[n]; cc = c_ext[n]; ww = weights[n]; }
        const float c2 = cc * cc;
        const float cl = c2 * LOG2E;
        const float s3 = valid ? (K_2_SQRT_PI * ww * c2 * cc) : 0.0f;
        const float q  = __builtin_amdgcn_exp2f(-2.0f * cl * dB * dB);
        const int p = tid >> 1, k = tid & 1;
        float* pA = (float*)sA;
        float* pB = (float*)sB;
        pA[4 * p + k]     = bm;
        pA[4 * p + 2 + k] = cl;
        pB[4 * p + k]     = s3;
        pB[4 * p + 2 + k] = q;
    }
    __syncthreads();

    const int ft  = blockIdx.y;
    const int f0g = ft * NFT + tid * FPT;
    const float bv = (f0g < n_fields) ? B_val[f0g] : 0.0f;

    const v2f ndB2  = { -dB, -dB };
    const float twodB = 2.0f * dB;
    const float nhdB  = -0.5f * dB;

    v2f acc[FPT];
#pragma unroll
    for (int k = 0; k < FPT; ++k) acc[k] = (v2f){0.0f, 0.0f};

#pragma unroll 4
    for (int p = 0; p < CHUNK / 2; ++p) {
        const float4 a = sA[p];          // broadcast ds_read_b128
        const float4 b = sB[p];          // broadcast ds_read_b128
        const v2f bm2 = { a.x, a.y };
        const v2f cl2 = { a.z, a.w };
        const v2f s32 = { b.x, b.y };
        v2f q2        = { b.z, b.w };

        v2f d = bm2;
        d.x -= bv; d.y -= bv;
        const v2f A2  = { cl2.x * twodB, cl2.y * twodB };   // 2 cl dB
        const v2f Bc2 = { A2.x * nhdB,   A2.y * nhdB };     // -cl dB^2
        const v2f u   = { (cl2.x * d.x) * d.x, (cl2.y * d.y) * d.y };
        v2f g = { __builtin_amdgcn_exp2f(-u.x) * s32.x,
                  __builtin_amdgcn_exp2f(-u.y) * s32.y };
        v2f h = { __builtin_amdgcn_exp2f(fmaf(A2.x, d.x, Bc2.x)),
                  __builtin_amdgcn_exp2f(fmaf(A2.y, d.y, Bc2.y)) };

#pragma unroll
        for (int k = 0; k < FPT; ++k) {
            PK_FMA_ACC(acc[k], d, g);    // acc += d * g  (2 lines packed)
            if (k < FPT - 1) {
                PK_MUL_IN(g, h);         // g *= h
                PK_MUL_IN(h, q2);        // h *= q
                PK_ADD_IN(d, ndB2);      // d -= dB
            }
        }
    }

    // Combine line-slots; store this thread's 8-field partial (two float4).
    const int rowlen = nft * NFT;
    float* row = part + (size_t)blockIdx.x * rowlen + ft * NFT + tid * FPT;
    *reinterpret_cast<float4*>(row) =
        make_float4(acc[0].x + acc[0].y, acc[1].x + acc[1].y,
                    acc[2].x + acc[2].y, acc[3].x + acc[3].y);
    *reinterpret_cast<float4*>(row + 4) =
        make_float4(acc[4].x + acc[4].y, acc[5].x + acc[5].y,
                    acc[6].x + acc[6].y, acc[7].x + acc[7].y);
}

// ---------------- Stage 2: wide coalesced column-sum -> out ----------------
// Block covers 16 fields (4 float4 quads). 256 threads: quad = t&3
// (64 B contiguous per 4 lanes), row-slice = t>>2 (64 slices).
__global__ __launch_bounds__(256) void spectra_reduce_kernel(
    const float4* __restrict__ part4, float* __restrict__ out,
    int n_chunks, int n_fields, int rowlen4)   // rowlen4 = rowlen/4
{
    __shared__ float4 red[64][4];
    __shared__ float4 red2[8][4];
    const int t = threadIdx.x;
    const int q = t & 3;          // field-quad within the 16-field group
    const int s = t >> 2;         // row slice 0..63
    const int base4 = blockIdx.x * 4;

    float4 a = make_float4(0.f, 0.f, 0.f, 0.f);
    if (base4 + q < rowlen4) {
#pragma unroll 8
        for (int p = s; p < n_chunks; p += 64) {
            const float4 v = part4[(size_t)p * rowlen4 + base4 + q];
            a.x += v.x; a.y += v.y; a.z += v.z; a.w += v.w;
        }
    }
    red[s][q] = a;
    __syncthreads();

    if (t < 32) {
        const int qq = t & 3, g = t >> 2;   // g = 0..7
        float4 r = make_float4(0.f, 0.f, 0.f, 0.f);
#pragma unroll
        for (int k = 0; k < 8; ++k) {
            const float4 v = red[g * 8 + k][qq];
            r.x += v.x; r.y += v.y; r.z += v.z; r.w += v.w;
        }
        red2[g][qq] = r;
    }
    __syncthreads();

    if (t < 4) {
        float4 a0 = make_float4(0.f, 0.f, 0.f, 0.f);
#pragma unroll
        for (int g = 0; g < 8; ++g) {
            const float4 r = red2[g][t];
            a0.x += r.x; a0.y += r.y; a0.z += r.z; a0.w += r.w;
        }
        const int f = blockIdx.x * 16 + t * 4;
        if (f + 4 <= n_fields) {
            *reinterpret_cast<float4*>(&out[f]) = a0;
        } else {
            if (f + 0 < n_fields) out[f + 0] = a0.x;
            if (f + 1 < n_fields) out[f + 1] = a0.y;
            if (f + 2 < n_fields) out[f + 2] = a0.z;
            if (f + 3 < n_fields) out[f + 3] = a0.w;
        }
    }
}

// ---------------- Fallback (tiny ws): exact masked atomic path -----------
__global__ void zero_out_kernel(float* __restrict__ out, int n) {
    int i = blockIdx.x * blockDim.x + threadIdx.x;
    if (i < n) out[i] = 0.0f;
}

__global__ __launch_bounds__(1024) void spectra_atomic_kernel(
    const float* __restrict__ B_mean,
    const float* __restrict__ c_ext,
    const float* __restrict__ B_val,
    const float* __restrict__ weights,
    float* __restrict__ out,
    int n_lines, int n_fields)
{
    __shared__ float4 lds[256];
    const int tid  = threadIdx.x;
    const int base = blockIdx.x * 256;
    if (tid < 256) {
        const int n = base + tid;
        float bm = 0.0f, cc = 0.0f, ww = 0.0f;
        if (n < n_lines) { bm = B_mean[n]; cc = c_ext[n]; ww = weights[n]; }
        const float c2 = cc * cc;
        lds[tid] = make_float4(bm, c2 * LOG2E, K_2_SQRT_PI * ww * c2 * cc, 0.0f);
    }
    __syncthreads();
    const int f = tid;
    const float bv = (f < n_fields) ? B_val[f] : 0.0f;
    const int nl = min(256, n_lines - base);
    float acc = 0.0f;
#pragma unroll 4
    for (int i = 0; i < nl; ++i) {
        const float4 L = lds[i];
        const float d = L.x - bv;
        const float u = (L.y * d) * d;
        const float e = __builtin_amdgcn_exp2f(-u);
        acc += (L.z * d) * ((u <= 6.25f * LOG2E) ? e : 0.0f);
    }
    if (f < n_fields) atomicAdd(&out[f], acc);
}

extern "C" void kernel_launch(void* const* d_in, const int* in_sizes, int n_in,
                              void* d_out, int out_size, void* d_ws, size_t ws_size,
                              hipStream_t stream) {
    const float* B_mean  = (const float*)d_in[0];
    const float* c_ext   = (const float*)d_in[1];
    const float* B_val   = (const float*)d_in[2];
    const float* weights = (const float*)d_in[3];
    float* out = (float*)d_out;

    const int n_lines  = in_sizes[0];
    const int n_fields = in_sizes[2];

    const int n_chunks = (n_lines + CHUNK - 1) / CHUNK;
    const int nft      = (n_fields + NFT - 1) / NFT;
    const int rowlen   = nft * NFT;
    const size_t part_bytes = (size_t)n_chunks * rowlen * sizeof(float);

    if (part_bytes > ws_size || n_fields < 2) {
        zero_out_kernel<<<(out_size + 255) / 256, 256, 0, stream>>>(out, out_size);
        spectra_atomic_kernel<<<(n_lines + 255) / 256, 1024, 0, stream>>>(
            B_mean, c_ext, B_val, weights, out, n_lines, n_fields);
        return;
    }

    float* part = (float*)d_ws;

    dim3 grid1(n_chunks, nft);
    spectra_partial_kernel<<<grid1, BLOCK, 0, stream>>>(
        B_mean, c_ext, B_val, weights, part, n_lines, n_fields, nft);

    spectra_reduce_kernel<<<(rowlen + 15) / 16, 256, 0, stream>>>(
        reinterpret_cast<const float4*>(part), out,
        n_chunks, n_fields, rowlen / 4);
}